// Round 4
// baseline (267.197 us; speedup 1.0000x reference)
//
#include <hip/hip_runtime.h>
#include <hip/hip_bf16.h>

// Problem: B=64, Cin=64, Cout=128, H=W=64, K=3.
// ConvTranspose2d(stride=1,pad=0) -> spatial mean factorizes:
//   gap[b,o] = (1/4356) * sum_i Sx[b,i] * Sw[i,o] + bias[o]
//   out[b]   = 10 * logsumexp_o(gap[b,o])
// Fully fused: 4096 row-sum blocks; last-finishing block per batch runs
// that batch's gap+LSE epilogue (decoupled via device-scope counters).

#define HW 4096
#define CIN 64
#define COUT 128
#define BATCH 64
#define INV_AREA (1.0f / 4356.0f)   // 1/(66*66)

typedef float f4 __attribute__((ext_vector_type(4)));

// d_ws layout (floats): sx[4096] | sws[8192] | cnt_b[64] | cnt_sws[1]
#define SX_OFF   0
#define SWS_OFF  4096
#define CNTB_OFF (4096 + 8192)
#define CNTS_OFF (4096 + 8192 + 64)

__global__ __launch_bounds__(256) void fused_kernel(
    const float* __restrict__ x, const float* __restrict__ weight,
    const float* __restrict__ bias, float* __restrict__ out,
    float* __restrict__ ws)
{
    float* sx      = ws + SX_OFF;
    float* sws     = ws + SWS_OFF;
    int*   cnt_b   = (int*)(ws + CNTB_OFF);
    int*   cnt_sws = (int*)(ws + CNTS_OFF);

    const int row = blockIdx.x;          // 0..4095  (= b*64 + i)
    const int b   = row >> 6;
    const int t   = threadIdx.x;

    // ---- Side duty: Sw table, 16 blocks x 256 entries = 8192 ----
    if (row < (CIN * COUT) / 256) {
        const int p = row * 256 + t;
        const float* wp = weight + (size_t)p * 9;
        float sw = 0.0f;
#pragma unroll
        for (int k = 0; k < 9; ++k) sw += wp[k];
        sws[p] = sw;
        __threadfence();
        __syncthreads();                 // all sws stores done block-wide
        if (t == 0) __hip_atomic_fetch_add(cnt_sws, 1, __ATOMIC_RELEASE,
                                           __HIP_MEMORY_SCOPE_AGENT);
    }

    // ---- Row sum: 4096 floats, 4x f4 per thread, nontemporal ----
    const f4* p4 = reinterpret_cast<const f4*>(x) + (size_t)row * (HW / 4);
    float s = 0.0f;
#pragma unroll
    for (int k = 0; k < 4; ++k) {
        f4 v = __builtin_nontemporal_load(&p4[t + k * 256]);
        s += (v.x + v.y) + (v.z + v.w);
    }
#pragma unroll
    for (int off = 32; off > 0; off >>= 1)
        s += __shfl_xor(s, off, 64);

    __shared__ float wsum[4];
    __shared__ int flag;
    if ((t & 63) == 0) wsum[t >> 6] = s;
    __syncthreads();

    if (t == 0) {
        sx[row] = (wsum[0] + wsum[1]) + (wsum[2] + wsum[3]);
        __threadfence();                 // publish sx before counting
        int old = __hip_atomic_fetch_add(&cnt_b[b], 1, __ATOMIC_ACQ_REL,
                                         __HIP_MEMORY_SCOPE_AGENT);
        flag = (old == CIN - 1);         // last block of this batch?
    }
    __syncthreads();
    if (!flag) return;

    // ---- Epilogue for batch b (one block, L2-hot data) ----
    if (t == 0) {
        while (__hip_atomic_load(cnt_sws, __ATOMIC_ACQUIRE,
                                 __HIP_MEMORY_SCOPE_AGENT) < 16) { }
        __threadfence();
    }
    __syncthreads();

    __shared__ float sxs[CIN];
    if (t < CIN) sxs[t] = sx[b * CIN + t];
    __syncthreads();

    const int o = t;                     // channel for t<128
    float gap = -INFINITY;
    if (o < COUT) {
        float acc = 0.0f;
#pragma unroll
        for (int i = 0; i < CIN; ++i)
            acc = fmaf(sxs[i], sws[i * COUT + o], acc);
        gap = fmaf(acc, INV_AREA, bias[o]);
    }

    // logsumexp over o=0..127 (waves 0 and 1)
    float m = gap;
#pragma unroll
    for (int off = 32; off > 0; off >>= 1)
        m = fmaxf(m, __shfl_xor(m, off, 64));

    __shared__ float wmax[2], wacc[2];
    if (o < COUT && (o & 63) == 0) wmax[o >> 6] = m;
    __syncthreads();
    const float M = fmaxf(wmax[0], wmax[1]);

    float e = (o < COUT) ? __expf(gap - M) : 0.0f;
#pragma unroll
    for (int off = 32; off > 0; off >>= 1)
        e += __shfl_xor(e, off, 64);
    if (o < COUT && (o & 63) == 0) wacc[o >> 6] = e;
    __syncthreads();

    if (t == 0)
        out[b] = 10.0f * (logf(wacc[0] + wacc[1]) + M);
}

extern "C" void kernel_launch(void* const* d_in, const int* in_sizes, int n_in,
                              void* d_out, int out_size, void* d_ws, size_t ws_size,
                              hipStream_t stream) {
    const float* x      = (const float*)d_in[0];  // (64,64,64,64)
    const float* weight = (const float*)d_in[1];  // (64,128,3,3)
    const float* bias   = (const float*)d_in[2];  // (128,1,1)
    float* out = (float*)d_out;                   // 64 floats
    float* ws  = (float*)d_ws;

    // zero the counters (cnt_b[64] + cnt_sws[1]) each launch
    hipMemsetAsync(ws + CNTB_OFF, 0, (BATCH + 1) * sizeof(int), stream);
    fused_kernel<<<BATCH * CIN, 256, 0, stream>>>(x, weight, bias, out, ws);
}

// Round 5
// 49.215 us; speedup vs baseline: 5.4291x; 5.4291x over previous
//
#include <hip/hip_runtime.h>
#include <hip/hip_bf16.h>

// Problem: B=64, Cin=64, Cout=128, H=W=64, K=3.
// ConvTranspose2d(stride=1,pad=0) -> spatial mean factorizes:
//   gap[b,o] = (1/4356) * sum_i Sx[b,i] * Sw[i,o] + bias[o]
//   out[b]   = 10 * logsumexp_o(gap[b,o])
// Single fused kernel. Cross-block publication uses RELAXED agent-scope
// atomics only (write-through to LLC, no L2 writeback/invalidate ops —
// R4 showed per-block __threadfence costs ~75ns x 4096 = 300us).

#define HW 4096
#define CIN 64
#define COUT 128
#define BATCH 64
#define INV_AREA (1.0f / 4356.0f)   // 1/(66*66)
#define NSWSBLK 32                  // 8192 sws entries / 256 threads

typedef float f4 __attribute__((ext_vector_type(4)));

// d_ws layout (floats): sx[4096] | sws[8192] | cnt_b[64] | cnt_sws[1]
#define SX_OFF   0
#define SWS_OFF  4096
#define CNTB_OFF (4096 + 8192)
#define CNTS_OFF (CNTB_OFF + 64)

__device__ __forceinline__ void st_agent(float* p, float v) {
    __hip_atomic_store(p, v, __ATOMIC_RELAXED, __HIP_MEMORY_SCOPE_AGENT);
}
__device__ __forceinline__ float ld_agent(const float* p) {
    return __hip_atomic_load(p, __ATOMIC_RELAXED, __HIP_MEMORY_SCOPE_AGENT);
}

__global__ __launch_bounds__(256) void fused_kernel(
    const float* __restrict__ x, const float* __restrict__ weight,
    const float* __restrict__ bias, float* __restrict__ out,
    float* __restrict__ ws)
{
    float* sx      = ws + SX_OFF;
    float* sws     = ws + SWS_OFF;
    int*   cnt_b   = (int*)(ws + CNTB_OFF);
    int*   cnt_sws = (int*)(ws + CNTS_OFF);

    const int row = blockIdx.x;          // 0..4095  (= b*64 + i)
    const int b   = row >> 6;
    const int t   = threadIdx.x;

    // ---- Side duty (rows 0..31 = batch 0): Sw table, 32 x 256 = 8192 ----
    if (row < NSWSBLK) {
        const int p = row * 256 + t;
        const float* wp = weight + (size_t)p * 9;
        float sw = 0.0f;
#pragma unroll
        for (int k = 0; k < 9; ++k) sw += wp[k];
        st_agent(&sws[p], sw);                       // write-through to LLC
        asm volatile("s_waitcnt vmcnt(0)" ::: "memory");  // my store is done
        __syncthreads();                             // whole block's stores done
        if (t == 0)
            __hip_atomic_fetch_add(cnt_sws, 1, __ATOMIC_RELAXED,
                                   __HIP_MEMORY_SCOPE_AGENT);
    }

    // ---- Row sum: 4096 floats, 4x f4 per thread, nontemporal ----
    const f4* p4 = reinterpret_cast<const f4*>(x) + (size_t)row * (HW / 4);
    float s = 0.0f;
#pragma unroll
    for (int k = 0; k < 4; ++k) {
        f4 v = __builtin_nontemporal_load(&p4[t + k * 256]);
        s += (v.x + v.y) + (v.z + v.w);
    }
#pragma unroll
    for (int off = 32; off > 0; off >>= 1)
        s += __shfl_xor(s, off, 64);

    __shared__ float wsum[4];
    __shared__ int flag;
    if ((t & 63) == 0) wsum[t >> 6] = s;
    __syncthreads();

    if (t == 0) {
        float rs = (wsum[0] + wsum[1]) + (wsum[2] + wsum[3]);
        st_agent(&sx[row], rs);                      // write-through to LLC
        asm volatile("s_waitcnt vmcnt(0)" ::: "memory");
        int old = __hip_atomic_fetch_add(&cnt_b[b], 1, __ATOMIC_RELAXED,
                                         __HIP_MEMORY_SCOPE_AGENT);
        flag = (old == CIN - 1);                     // last block of batch b?
    }
    __syncthreads();
    if (!flag) return;

    // ---- Epilogue for batch b (counter-guaranteed data is at LLC) ----
    if (t == 0) {   // safety net; in practice already 32 (producers are batch 0)
        while (__hip_atomic_load(cnt_sws, __ATOMIC_RELAXED,
                                 __HIP_MEMORY_SCOPE_AGENT) < NSWSBLK) { }
    }
    __syncthreads();

    __shared__ float sxs[CIN];
    if (t < CIN) sxs[t] = ld_agent(&sx[b * CIN + t]);
    __syncthreads();

    float gap = -INFINITY;
    if (t < COUT) {
        float acc = 0.0f;
#pragma unroll
        for (int i = 0; i < CIN; ++i)                // lanes index o: coalesced
            acc = fmaf(sxs[i], ld_agent(&sws[i * COUT + t]), acc);
        gap = fmaf(acc, INV_AREA, bias[t]);
    }

    // logsumexp across the block (channels live in waves 0-1; 2-3 are -inf/0)
    float m = gap;
#pragma unroll
    for (int off = 32; off > 0; off >>= 1)
        m = fmaxf(m, __shfl_xor(m, off, 64));

    __shared__ float wmax[4], wacc[4];
    if ((t & 63) == 0) wmax[t >> 6] = m;
    __syncthreads();
    const float M = fmaxf(fmaxf(wmax[0], wmax[1]), fmaxf(wmax[2], wmax[3]));

    float e = (t < COUT) ? __expf(gap - M) : 0.0f;
#pragma unroll
    for (int off = 32; off > 0; off >>= 1)
        e += __shfl_xor(e, off, 64);
    if ((t & 63) == 0) wacc[t >> 6] = e;
    __syncthreads();

    if (t == 0)
        out[b] = 10.0f * (logf((wacc[0] + wacc[1]) + (wacc[2] + wacc[3])) + M);
}

extern "C" void kernel_launch(void* const* d_in, const int* in_sizes, int n_in,
                              void* d_out, int out_size, void* d_ws, size_t ws_size,
                              hipStream_t stream) {
    const float* x      = (const float*)d_in[0];  // (64,64,64,64)
    const float* weight = (const float*)d_in[1];  // (64,128,3,3)
    const float* bias   = (const float*)d_in[2];  // (128,1,1)
    float* out = (float*)d_out;                   // 64 floats
    float* ws  = (float*)d_ws;

    // zero cnt_b[64] + cnt_sws[1] each launch (stream-ordered, capture-safe)
    hipMemsetAsync(ws + CNTB_OFF, 0, (BATCH + 1) * sizeof(int), stream);
    fused_kernel<<<BATCH * CIN, 256, 0, stream>>>(x, weight, bias, out, ws);
}

// Round 6
// 17.314 us; speedup vs baseline: 15.4321x; 2.8425x over previous
//
#include <hip/hip_runtime.h>
#include <hip/hip_bf16.h>

// Problem: B=64, Cin=64, Cout=128, H=W=64, K=3.
// ConvTranspose2d(stride=1,pad=0) -> spatial mean factorizes:
//   gap[b,o] = (1/4356) * sum_i Sx[b,i] * Sw[i,o] + bias[o]
//   out[b]   = 10 * logsumexp_o(gap[b,o])
// Two kernels; the kernel boundary is the (free) global barrier.
// Kernel 1 is a pure streamer: one wave per row, no LDS/sync/atomics.

#define HW 4096          // 64*64 spatial elements per (b,i) row
#define CIN 64
#define COUT 128
#define BATCH 64
#define INV_AREA (1.0f / 4356.0f)   // 1/(66*66)

typedef float f4 __attribute__((ext_vector_type(4)));

// ---------------- Kernel 1: spatial sums of x + Sw side-duty -----------
// 1024 blocks x 256 threads. Wave w sums row 4*blk+w (1024 f4, 16/lane).
// Blocks 0..31 additionally compute 256 Sw entries each (8192 total).
__global__ __launch_bounds__(256) void spatial_sum_kernel(
    const float* __restrict__ x, const float* __restrict__ weight,
    float* __restrict__ sx, float* __restrict__ sws)
{
    const int t   = threadIdx.x;
    const int blk = blockIdx.x;              // 0 .. 1023

    // Side duty: Sw[p], p = i*128+o. 32 blocks x 256 threads = 8192 entries.
    if (blk < (CIN * COUT) / 256) {
        const int p = blk * 256 + t;
        const float* wp = weight + (size_t)p * 9;
        float sw = 0.0f;
#pragma unroll
        for (int k = 0; k < 9; ++k) sw += wp[k];
        sws[p] = sw;                         // plain store; kernel boundary publishes
    }

    const int wid  = t >> 6;
    const int lane = t & 63;
    const int row  = blk * 4 + wid;          // one wave per row
    const f4* p4 = reinterpret_cast<const f4*>(x) + (size_t)row * (HW / 4);

    float s = 0.0f;
#pragma unroll
    for (int k = 0; k < 16; ++k) {           // 16 independent 1KB-coalesced loads
        f4 v = __builtin_nontemporal_load(&p4[k * 64 + lane]);
        s += (v.x + v.y) + (v.z + v.w);
    }
#pragma unroll
    for (int off = 32; off > 0; off >>= 1)
        s += __shfl_xor(s, off, 64);

    if (lane == 0) sx[row] = s;              // plain store; no wait needed
}

// ---------------- Kernel 2: gap + logsumexp epilogue -------------------
// One block per batch b; 128 threads = one per output channel o.
__global__ __launch_bounds__(128) void gap_lse_kernel(
    const float* __restrict__ sx,      // (B, Cin)
    const float* __restrict__ sws,     // (Cin, Cout) pre-summed kernel taps
    const float* __restrict__ bias,    // (Cout)
    float* __restrict__ out)           // (B)
{
    const int b = blockIdx.x;
    const int o = threadIdx.x;         // 0 .. 127

    __shared__ float sxs[CIN];
    if (o < CIN) sxs[o] = sx[b * CIN + o];
    __syncthreads();

    // 64 independent coalesced L2-hit loads, fully unrolled.
    float acc = 0.0f;
#pragma unroll
    for (int i = 0; i < CIN; ++i)
        acc = fmaf(sxs[i], sws[i * COUT + o], acc);
    const float gap = fmaf(acc, INV_AREA, bias[o]);

    // logsumexp across 128 threads (2 waves)
    float m = gap;
#pragma unroll
    for (int off = 32; off > 0; off >>= 1)
        m = fmaxf(m, __shfl_xor(m, off, 64));

    __shared__ float wmax[2], wacc[2];
    const int wid = o >> 6;
    if ((o & 63) == 0) wmax[wid] = m;
    __syncthreads();
    const float M = fmaxf(wmax[0], wmax[1]);

    float e = __expf(gap - M);
#pragma unroll
    for (int off = 32; off > 0; off >>= 1)
        e += __shfl_xor(e, off, 64);
    if ((o & 63) == 0) wacc[wid] = e;
    __syncthreads();

    if (o == 0)
        out[b] = 10.0f * (logf(wacc[0] + wacc[1]) + M);
}

extern "C" void kernel_launch(void* const* d_in, const int* in_sizes, int n_in,
                              void* d_out, int out_size, void* d_ws, size_t ws_size,
                              hipStream_t stream) {
    const float* x      = (const float*)d_in[0];  // (64,64,64,64)
    const float* weight = (const float*)d_in[1];  // (64,128,3,3)
    const float* bias   = (const float*)d_in[2];  // (128,1,1)
    float* out = (float*)d_out;                   // 64 floats
    float* sx  = (float*)d_ws;                    // (64,64) scratch
    float* sws = (float*)d_ws + BATCH * CIN;      // (64,128) scratch

    spatial_sum_kernel<<<(BATCH * CIN) / 4, 256, 0, stream>>>(x, weight, sx, sws);
    gap_lse_kernel<<<BATCH, 128, 0, stream>>>(sx, sws, bias, out);
}